// Round 8
// baseline (146.999 us; speedup 1.0000x reference)
//
#include <hip/hip_runtime.h>

// STFT: x[16, 262144] fp32, Hann 2048, hop 512, reflect pad 1024.
// Output: real[16,1025,513] ++ imag[16,1025,513], fp32.
//
// Round 8: staged, all stores full-sector (ECC HBM makes partial-sector masked
// writebacks ~3x RMW cost -- R7's fused kernel drained 124 MB at only 2.2 TB/s).
// Harness ws poison is constant overhead (present since R1) -> d_ws is free.
//  A) stft_fft8: one packed complex FFT (2 frames) per 256-thread block,
//     17 KB LDS -> 8 blocks/CU (barriers hidden). R7 radix-8 register core
//     (3 octet passes + 1 quad pass, __sincosf twiddles). Writes spec2
//     [b][f][k] float2 in contiguous 8.2 KB rows (write amp ~1.01).
//  B) transpose_aligned: per-row 64 B-ALIGNED write windows. Row (b,k) has
//     shift a = (-rowbase) mod 16; block fj writes f in [128*fj+a, 128*(fj+1)+a)
//     (clamped to [0,513)), loading a 144-frame halo tile from spec2. All
//     interior stores are full aligned sectors; only 2 partial sectors per row
//     (f=0 head, f=513 tail).
// Fallback: R7 fused kernel if ws is too small (it isn't: 269 MB poisons).

#define N_FFT   2048
#define LOG2N   11
#define HOP     512
#define PADL    1024
#define NBINS   1025
#define NFRAMES 513
#define NBATCH  16
#define TLEN    262144

#define HALF_OUT ((size_t)NBATCH * NBINS * NFRAMES)   // 8,413,200 floats per plane

__device__ __forceinline__ int pidx(int a) { return a + (a >> 5); }

__device__ __forceinline__ int refl(int j) {
    if (j < 0)          j = -j;
    else if (j >= TLEN) j = 2 * TLEN - 2 - j;
    return j;
}

__device__ __forceinline__ float2 cmul(float2 a, float2 w) {
    return make_float2(fmaf(a.x, w.x, -a.y * w.y), fmaf(a.x, w.y, a.y * w.x));
}
__device__ __forceinline__ float2 cadd(float2 a, float2 b) {
    return make_float2(a.x + b.x, a.y + b.y);
}
__device__ __forceinline__ float2 csub(float2 a, float2 b) {
    return make_float2(a.x - b.x, a.y - b.y);
}
__device__ __forceinline__ float2 csqr(float2 w) {
    return make_float2(fmaf(w.x, w.x, -w.y * w.y), 2.0f * w.x * w.y);
}

// Three DIT stages (halves H, 2H, 4H) on points base + m*H, m=0..7, in registers.
template <int H, int L2H>
__device__ __forceinline__ void octet_pass(float2* __restrict__ zc, int q) {
    const int p    = q & (H - 1);
    const int base = ((q >> L2H) << (L2H + 3)) + p;
    int ia[8];
#pragma unroll
    for (int m = 0; m < 8; ++m) ia[m] = pidx(base + m * H);
    float2 v0 = zc[ia[0]], v1 = zc[ia[1]], v2 = zc[ia[2]], v3 = zc[ia[3]];
    float2 v4 = zc[ia[4]], v5 = zc[ia[5]], v6 = zc[ia[6]], v7 = zc[ia[7]];

    float2 w1, w2, w3;
    if (H == 1) {
        w3 = make_float2(1.0f, 0.0f); w2 = w3; w1 = w3;
    } else {
        float s, c;
        __sincosf((float)p * (-3.14159265358979323846f / (4.0f * (float)H)), &s, &c);
        w3 = make_float2(c, s);
        w2 = csqr(w3);
        w1 = csqr(w2);
    }

    float2 t;
    t = cmul(v1, w1); v1 = csub(v0, t); v0 = cadd(v0, t);
    t = cmul(v3, w1); v3 = csub(v2, t); v2 = cadd(v2, t);
    t = cmul(v5, w1); v5 = csub(v4, t); v4 = cadd(v4, t);
    t = cmul(v7, w1); v7 = csub(v6, t); v6 = cadd(v6, t);
    const float2 w2m = make_float2(w2.y, -w2.x);
    t = cmul(v2, w2);  v2 = csub(v0, t); v0 = cadd(v0, t);
    t = cmul(v3, w2m); v3 = csub(v1, t); v1 = cadd(v1, t);
    t = cmul(v6, w2);  v6 = csub(v4, t); v4 = cadd(v4, t);
    t = cmul(v7, w2m); v7 = csub(v5, t); v5 = cadd(v5, t);
    const float R = 0.70710678118654752f;
    const float2 w3o  = make_float2((w3.x + w3.y) * R, (w3.y - w3.x) * R);
    const float2 w3m  = make_float2(w3.y, -w3.x);
    const float2 w3mo = make_float2(w3o.y, -w3o.x);
    t = cmul(v4, w3);   v4 = csub(v0, t); v0 = cadd(v0, t);
    t = cmul(v5, w3o);  v5 = csub(v1, t); v1 = cadd(v1, t);
    t = cmul(v6, w3m);  v6 = csub(v2, t); v2 = cadd(v2, t);
    t = cmul(v7, w3mo); v7 = csub(v3, t); v3 = cadd(v3, t);

    zc[ia[0]] = v0; zc[ia[1]] = v1; zc[ia[2]] = v2; zc[ia[3]] = v3;
    zc[ia[4]] = v4; zc[ia[5]] = v5; zc[ia[6]] = v6; zc[ia[7]] = v7;
}

// ---------- Kernel A: one packed FFT (frames 2g, 2g+1) per block ----------
__global__ __launch_bounds__(256) void stft_fft8(
    const float* __restrict__ x,
    const float* __restrict__ window,
    float2* __restrict__ spec2)        // [b][f][k] interleaved
{
    __shared__ float2 z[2112];         // pidx(2047)=2110 -> 16.9 KB -> 8 blocks/CU

    const int g   = blockIdx.x;        // frame pair
    const int b   = blockIdx.y;
    const int t   = threadIdx.x;
    const int fa  = 2 * g;
    const bool hasb = (fa + 1) < NFRAMES;

    const float* xb = x + (size_t)b * TLEN;
    const int basea = fa * HOP - PADL;
    const int baseb = (fa + 1) * HOP - PADL;   // phantom frame reads valid data
#pragma unroll
    for (int it = 0; it < 8; ++it) {
        const int n = t + it * 256;
        const float w  = window[n];
        const float va = xb[refl(basea + n)] * w;
        const float vb = xb[refl(baseb + n)] * w;
        const int r = (int)(__brev((unsigned)n) >> (32 - LOG2N));
        z[pidx(r)] = make_float2(va, vb);
    }
    __syncthreads();

    octet_pass<1, 0>(z, t);   __syncthreads();
    octet_pass<8, 3>(z, t);   __syncthreads();
    octet_pass<64, 6>(z, t);  __syncthreads();

    // stages 10-11: radix-4 quad pass (h=512), 512 items
#pragma unroll
    for (int it = 0; it < 2; ++it) {
        const int p = t + it * 256;
        float s, cc;
        __sincosf((float)p * (-3.14159265358979323846f / 1024.0f), &s, &cc);
        const float2 w2  = make_float2(cc, s);
        const float2 w1  = csqr(w2);
        const float2 w2m = make_float2(w2.y, -w2.x);
        const int i0 = pidx(p), i1 = pidx(p + 512), i2 = pidx(p + 1024), i3 = pidx(p + 1536);
        float2 v0 = z[i0], v1 = z[i1], v2 = z[i2], v3 = z[i3];
        float2 tt;
        tt = cmul(v1, w1); v1 = csub(v0, tt); v0 = cadd(v0, tt);
        tt = cmul(v3, w1); v3 = csub(v2, tt); v2 = cadd(v2, tt);
        tt = cmul(v2, w2);  v2 = csub(v0, tt); v0 = cadd(v0, tt);
        tt = cmul(v3, w2m); v3 = csub(v1, tt); v1 = cadd(v1, tt);
        z[i0] = v0; z[i1] = v1; z[i2] = v2; z[i3] = v3;
    }
    __syncthreads();

    // unpack two real spectra; contiguous 8.2 KB rows
    const size_t rowa = ((size_t)b * NFRAMES + fa) * NBINS;
    const size_t rowb = rowa + NBINS;
    for (int k = t; k < NBINS; k += 256) {
        const float2 zk = z[pidx(k)];
        const float2 zr = z[pidx((N_FFT - k) & (N_FFT - 1))];
        spec2[rowa + k] = make_float2(0.5f * (zk.x + zr.x), 0.5f * (zk.y - zr.y));
        if (hasb)
            spec2[rowb + k] = make_float2(0.5f * (zk.y + zr.y), 0.5f * (zr.x - zk.x));
    }
}

// ---------- Kernel B: transpose with per-row 64 B-aligned write windows ----------
__global__ __launch_bounds__(256) void transpose_aligned(
    const float2* __restrict__ spec2,
    float* __restrict__ out)
{
    __shared__ float2 tile[144][65];   // 74.9 KB -> 2 blocks/CU

    const int fj = blockIdx.x;         // 0..3  (128-frame write windows)
    const int kt = blockIdx.y;         // 0..16 (64-bin tiles; kt=16 has 1 row)
    const int b  = blockIdx.z;
    const int F0 = fj * 128;
    const int k0 = kt * 64;
    const int tid = threadIdx.x;

    const float2* sp = spec2 + (size_t)b * NFRAMES * NBINS;
    for (int i = tid; i < 144 * 64; i += 256) {
        const int fl  = i >> 6;
        const int kin = i & 63;
        const int f = F0 + fl;
        const int k = k0 + kin;
        tile[fl][kin] = (f < NFRAMES && k < NBINS) ? sp[(size_t)f * NBINS + k]
                                                   : make_float2(0.0f, 0.0f);
    }
    __syncthreads();

    float* __restrict__ outr = out;
    float* __restrict__ outi = out + HALF_OUT;
    for (int i = tid; i < 64 * 144; i += 256) {
        const int kin = i / 144;
        const int j   = i - kin * 144;
        const int k   = k0 + kin;
        if (k >= NBINS) continue;
        const size_t rowbase = ((size_t)b * NBINS + k) * NFRAMES;
        const int a  = (int)((16 - (rowbase & 15)) & 15);   // floats to 64 B boundary
        const int W0 = (fj == 0) ? 0       : F0 + a;
        const int W1 = (fj == 3) ? NFRAMES : F0 + 128 + a;
        const int f  = W0 + j;
        if (f < W1) {
            const float2 v = tile[f - F0][kin];
            outr[rowbase + f] = v.x;
            outi[rowbase + f] = v.y;
        }
    }
}

// ---------- Fallback (R7 fused, known good) ----------
__global__ __launch_bounds__(1024) void stft_one(
    const float* __restrict__ x,
    const float* __restrict__ window,
    float* __restrict__ out)
{
    __shared__ float2 z[9][2112];

    const int d     = blockIdx.x + 32 * blockIdx.y;
    const int pair  = (d >> 4) * 8 + (d & 7);
    const int gg    = 2 * pair + ((d >> 3) & 1);
    const int b     = gg >> 5;
    const int g     = gg & 31;
    const int tid   = threadIdx.x;
    const int f0    = g * 16;
    const int nsub  = (g == 31) ? 9 : 8;

    const float* xb = x + (size_t)b * TLEN;
    for (int idx = tid; idx < nsub * 2048; idx += 1024) {
        const int c  = idx >> 11;
        const int n  = idx & 2047;
        const int fa = f0 + 2 * c;
        const float w  = window[n];
        const float va = xb[refl(fa * HOP - PADL + n)] * w;
        const float vb = xb[refl((fa + 1) * HOP - PADL + n)] * w;
        const int r = (int)(__brev((unsigned)n) >> (32 - LOG2N));
        z[c][pidx(r)] = make_float2(va, vb);
    }
    __syncthreads();

    for (int idx = tid; idx < nsub * 256; idx += 1024)
        octet_pass<1, 0>(z[idx >> 8], idx & 255);
    __syncthreads();
    for (int idx = tid; idx < nsub * 256; idx += 1024)
        octet_pass<8, 3>(z[idx >> 8], idx & 255);
    __syncthreads();
    for (int idx = tid; idx < nsub * 256; idx += 1024)
        octet_pass<64, 6>(z[idx >> 8], idx & 255);
    __syncthreads();

    for (int idx = tid; idx < nsub * 512; idx += 1024) {
        const int c = idx >> 9;
        const int p = idx & 511;
        float s, cc;
        __sincosf((float)p * (-3.14159265358979323846f / 1024.0f), &s, &cc);
        const float2 w2  = make_float2(cc, s);
        const float2 w1  = csqr(w2);
        const float2 w2m = make_float2(w2.y, -w2.x);
        const int i0 = pidx(p), i1 = pidx(p + 512), i2 = pidx(p + 1024), i3 = pidx(p + 1536);
        float2 v0 = z[c][i0], v1 = z[c][i1], v2 = z[c][i2], v3 = z[c][i3];
        float2 t;
        t = cmul(v1, w1); v1 = csub(v0, t); v0 = cadd(v0, t);
        t = cmul(v3, w1); v3 = csub(v2, t); v2 = cadd(v2, t);
        t = cmul(v2, w2);  v2 = csub(v0, t); v0 = cadd(v0, t);
        t = cmul(v3, w2m); v3 = csub(v1, t); v1 = cadd(v1, t);
        z[c][i0] = v0; z[c][i1] = v1; z[c][i2] = v2; z[c][i3] = v3;
    }
    __syncthreads();

    float* __restrict__ outr = out;
    float* __restrict__ outi = out + HALF_OUT;
    for (int k = tid; k < NBINS; k += 1024) {
        const int km = (N_FFT - k) & (N_FFT - 1);
        const size_t orow = ((size_t)b * NBINS + (size_t)k) * NFRAMES + (size_t)f0;
#pragma unroll
        for (int c = 0; c < 8; ++c) {
            const float2 zk = z[c][pidx(k)];
            const float2 zr = z[c][pidx(km)];
            outr[orow + 2 * c]     = 0.5f * (zk.x + zr.x);
            outr[orow + 2 * c + 1] = 0.5f * (zk.y + zr.y);
            outi[orow + 2 * c]     = 0.5f * (zk.y - zr.y);
            outi[orow + 2 * c + 1] = 0.5f * (zr.x - zk.x);
        }
        if (nsub == 9) {
            const float2 zk = z[8][pidx(k)];
            const float2 zr = z[8][pidx(km)];
            outr[orow + 16] = 0.5f * (zk.x + zr.x);
            outi[orow + 16] = 0.5f * (zk.y - zr.y);
        }
    }
}

extern "C" void kernel_launch(void* const* d_in, const int* in_sizes, int n_in,
                              void* d_out, int out_size, void* d_ws, size_t ws_size,
                              hipStream_t stream) {
    const float* x      = (const float*)d_in[0];
    const float* window = (const float*)d_in[1];
    float* out          = (float*)d_out;

    const size_t need = (size_t)NBATCH * NFRAMES * NBINS * sizeof(float2);  // 67.3 MB
    if (ws_size >= need) {
        float2* spec2 = (float2*)d_ws;
        dim3 ga((NFRAMES + 1) / 2, NBATCH);    // 257 x 16 = 4112 blocks
        stft_fft8<<<ga, 256, 0, stream>>>(x, window, spec2);
        dim3 gb(4, 17, NBATCH);                // 4 f-windows x 17 k-tiles x 16 b
        transpose_aligned<<<gb, 256, 0, stream>>>(spec2, out);
    } else {
        dim3 grid(32, NBATCH);
        stft_one<<<grid, 1024, 0, stream>>>(x, window, out);
    }
}